// Round 10
// baseline (356.749 us; speedup 1.0000x reference)
//
#include <hip/hip_runtime.h>
#include <hip/hip_bf16.h>

#define NN 10000
#define NPAD 10048   // 157 * 64
#define EE 320000
#define DD 256
#define LL 5

typedef __bf16 bf16x8 __attribute__((ext_vector_type(8)));
typedef __bf16 bf16x4 __attribute__((ext_vector_type(4)));
typedef float f32x4 __attribute__((ext_vector_type(4)));

__device__ __forceinline__ void gload_lds16(const void* g, void* l) {
    __builtin_amdgcn_global_load_lds(
        (const __attribute__((address_space(1))) void*)g,
        (__attribute__((address_space(3))) void*)l, 16, 0, 0);
}

// ---------------- setup kernels ----------------

// merged elementwise prep: whh conv, x conv, pad-zero, deg-zero
__global__ void prep_k(const float* __restrict__ w_hh, const float* __restrict__ x,
                       __bf16* __restrict__ whhb,
                       float* __restrict__ hb, __bf16* __restrict__ hbfA,
                       __bf16* __restrict__ hbfB, __bf16* __restrict__ aggb,
                       int* __restrict__ deg) {
    int i = blockIdx.x * blockDim.x + threadIdx.x;
    if (i < NN * DD) { float v = x[i]; hb[i] = v; hbfA[i] = (__bf16)v; }
    if (i < 768 * 256) whhb[i] = (__bf16)w_hh[i];
    if (i < (NPAD - NN) * DD) {
        hbfA[NN * DD + i] = (__bf16)0.f;
        hbfB[NN * DD + i] = (__bf16)0.f;
        aggb[NN * DD + i] = (__bf16)0.f;
    }
    if (i < NN) deg[i] = 0;
}

__global__ void hist_k(const int* __restrict__ dst, int* __restrict__ deg) {
    int e = blockIdx.x * blockDim.x + threadIdx.x;
    if (e < EE) atomicAdd(&deg[dst[e]], 1);
}

__global__ void scan_k(const int* __restrict__ deg, int* __restrict__ row_start,
                       int* __restrict__ cursor) {
    __shared__ int sums[1024];
    const int CH = 10;
    int t = threadIdx.x;
    int base = t * CH;
    int loc[CH];
    int s = 0;
#pragma unroll
    for (int i = 0; i < CH; i++) {
        int v = (base + i < NN) ? deg[base + i] : 0;
        loc[i] = s;
        s += v;
    }
    sums[t] = s;
    __syncthreads();
    for (int off = 1; off < 1024; off <<= 1) {
        int v = (t >= off) ? sums[t - off] : 0;
        __syncthreads();
        sums[t] += v;
        __syncthreads();
    }
    int pre = (t == 0) ? 0 : sums[t - 1];
#pragma unroll
    for (int i = 0; i < CH; i++) {
        int idx = base + i;
        if (idx < NN) {
            int v = pre + loc[i];
            row_start[idx] = v;
            cursor[idx] = v;
        }
    }
    if (t == 1023) row_start[NN] = sums[1023];
}

__global__ void fill_k(const int* __restrict__ ei, const float* __restrict__ attr,
                       int* __restrict__ cursor, int* __restrict__ ssrc,
                       float* __restrict__ sattr) {
    int e = blockIdx.x * blockDim.x + threadIdx.x;
    if (e < EE) {
        int dv = ei[EE + e];
        int p = atomicAdd(&cursor[dv], 1);
        ssrc[p] = ei[e];
        sattr[p] = attr[e];
    }
}

// ---------------- beff[l][j][t] = sum_d w_ih[j][d] * W[l][t][d], PURE FP32 ----------------
// single rounding to bf16 at the end. [768x256]x[256x256] NT per layer; grid (12,4,L).

__global__ __launch_bounds__(256)
void beff32_k(const float* __restrict__ wih, const float* __restrict__ W,
              __bf16* __restrict__ beff) {
    __shared__ float As[16][68];
    __shared__ float Bs[16][68];
    int l = blockIdx.z;
    const float* Wl = W + (size_t)l * DD * DD;
    __bf16* Cl = beff + (size_t)l * 768 * DD;
    int tid = threadIdx.x;
    int tx = tid & 15, ty = tid >> 4;
    int jBase = blockIdx.x * 64;
    int tBase = blockIdx.y * 64;
    int lr = tid >> 2, lq = tid & 3;
    float acc[4][4];
#pragma unroll
    for (int i = 0; i < 4; i++)
#pragma unroll
        for (int j = 0; j < 4; j++) acc[i][j] = 0.f;

    for (int k0 = 0; k0 < DD; k0 += 16) {
        float4 av = *(const float4*)(wih + (size_t)(jBase + lr) * DD + k0 + lq * 4);
        float4 bv = *(const float4*)(Wl + (size_t)(tBase + lr) * DD + k0 + lq * 4);
        __syncthreads();
        As[lq * 4 + 0][lr] = av.x; As[lq * 4 + 1][lr] = av.y;
        As[lq * 4 + 2][lr] = av.z; As[lq * 4 + 3][lr] = av.w;
        Bs[lq * 4 + 0][lr] = bv.x; Bs[lq * 4 + 1][lr] = bv.y;
        Bs[lq * 4 + 2][lr] = bv.z; Bs[lq * 4 + 3][lr] = bv.w;
        __syncthreads();
#pragma unroll
        for (int kk = 0; kk < 16; kk++) {
            float a0 = As[kk][ty * 4 + 0], a1 = As[kk][ty * 4 + 1];
            float a2 = As[kk][ty * 4 + 2], a3 = As[kk][ty * 4 + 3];
            float b0 = Bs[kk][tx * 4 + 0], b1 = Bs[kk][tx * 4 + 1];
            float b2 = Bs[kk][tx * 4 + 2], b3 = Bs[kk][tx * 4 + 3];
            acc[0][0] += a0 * b0; acc[0][1] += a0 * b1; acc[0][2] += a0 * b2; acc[0][3] += a0 * b3;
            acc[1][0] += a1 * b0; acc[1][1] += a1 * b1; acc[1][2] += a1 * b2; acc[1][3] += a1 * b3;
            acc[2][0] += a2 * b0; acc[2][1] += a2 * b1; acc[2][2] += a2 * b2; acc[2][3] += a2 * b3;
            acc[3][0] += a3 * b0; acc[3][1] += a3 * b1; acc[3][2] += a3 * b2; acc[3][3] += a3 * b3;
        }
    }
#pragma unroll
    for (int i = 0; i < 4; i++) {
        int j = jBase + ty * 4 + i;
        bf16x4 o;
        o[0] = (__bf16)acc[i][0]; o[1] = (__bf16)acc[i][1];
        o[2] = (__bf16)acc[i][2]; o[3] = (__bf16)acc[i][3];
        *(bf16x4*)(Cl + (size_t)j * DD + tBase + tx * 4) = o;
    }
}

// ---------------- aggregation: agg_raw[n,:] = sum_{e: dst=n} h[src_e,:]*attr_e ----------------
// wave per node; LDS-staged edge lists; 2 edges per bf16x8 gather; shfl_xor(32) combine

__global__ __launch_bounds__(256)
void aggregate_bf_k(const __bf16* __restrict__ hsrc, const int* __restrict__ row_start,
                    const int* __restrict__ ssrc, const float* __restrict__ sattr,
                    __bf16* __restrict__ aggb) {
    __shared__ int sIdx[4][64];
    __shared__ float sAtt[4][64];
    int w = threadIdx.x >> 6, lane = threadIdx.x & 63;
    int n = blockIdx.x * 4 + w;
    int s0 = row_start[n], s1 = row_start[n + 1];
    int half = lane >> 5;
    int c8 = (lane & 31) * 8;

    float acc[8] = {0.f, 0.f, 0.f, 0.f, 0.f, 0.f, 0.f, 0.f};

    for (int base = s0; base < s1; base += 64) {
        int cnt = min(64, s1 - base);
        if (lane < cnt) {
            sIdx[w][lane] = ssrc[base + lane];
            sAtt[w][lane] = sattr[base + lane];
        }
        int t = 0;
        for (; t + 8 <= cnt; t += 8) {
#pragma unroll
            for (int u = 0; u < 4; u++) {
                int e = t + u * 2 + half;
                int s = sIdx[w][e];
                float ww = sAtt[w][e];
                bf16x8 v = *(const bf16x8*)(hsrc + (size_t)s * DD + c8);
#pragma unroll
                for (int i = 0; i < 8; i++) acc[i] += (float)v[i] * ww;
            }
        }
        for (; t + 2 <= cnt; t += 2) {
            int e = t + half;
            int s = sIdx[w][e];
            float ww = sAtt[w][e];
            bf16x8 v = *(const bf16x8*)(hsrc + (size_t)s * DD + c8);
#pragma unroll
            for (int i = 0; i < 8; i++) acc[i] += (float)v[i] * ww;
        }
        if (t < cnt && half == 0) {
            int s = sIdx[w][t];
            float ww = sAtt[w][t];
            bf16x8 v = *(const bf16x8*)(hsrc + (size_t)s * DD + c8);
#pragma unroll
            for (int i = 0; i < 8; i++) acc[i] += (float)v[i] * ww;
        }
    }

#pragma unroll
    for (int i = 0; i < 8; i++) acc[i] += __shfl_xor(acc[i], 32, 64);

    if (half == 0) {
        bf16x8 o;
#pragma unroll
        for (int i = 0; i < 8; i++) o[i] = (__bf16)acc[i];
        *(bf16x8*)(aggb + (size_t)n * DD + c8) = o;
    }
}

// ---------------- fused GRU: LDS-staged 6-gate MFMA + gate math ----------------
// 512-thread blocks (8 waves), 64n x 64d tile, BK=64 (two 32-k sub-chunks, ascending k).
// per-wave tile: 16n x 32d x 6 gates (acc 48 VGPRs). 19.6 waves/CU latency hiding.
// LDS: sA [2 mats][2 ksub][64][32] 16KB + sB [6][2 ksub][64][32] 48KB = 64KB -> 2 blk/CU.

__global__ __launch_bounds__(512, 2)
void gru_mfma_k(const __bf16* __restrict__ aggb, const __bf16* __restrict__ hbf,
                const float* __restrict__ hin,
                const __bf16* __restrict__ bihw, const __bf16* __restrict__ whh,
                const float* __restrict__ b_ih, const float* __restrict__ b_hh,
                float* __restrict__ hout, __bf16* __restrict__ hbfout) {
    __shared__ __bf16 sA[2][2][64][32];
    __shared__ __bf16 sB[6][2][64][32];
    int tid = threadIdx.x;
    int wave = tid >> 6, lane = tid & 63;
    int ln = lane & 15, quad = lane >> 4;
    int nodeBlock = blockIdx.x * 64;
    int colBlock = blockIdx.y * 64;
    int nf = wave & 3;          // node frag (16 rows)
    int ch = (wave >> 2) * 32;  // col half (32 cols)
    int r4 = lane >> 2;         // 0..15
    int kb = (lane & 3) * 8;    // 8-elem offset within 32-k sub-chunk

    f32x4 acc[6][2] = {};       // [gate][colFrag16]

    for (int k0 = 0; k0 < DD; k0 += 64) {
        __syncthreads();
        // 64 staging insts: 8 per wave. idx<16 -> A (mat,ksub,rg), else B (gate,ksub,rg)
#pragma unroll
        for (int ii = 0; ii < 8; ii++) {
            int idx = wave * 8 + ii;
            const __bf16* src;
            __bf16* dst;
            if (idx < 16) {
                int mat = idx >> 3;        // 0 = agg, 1 = h
                int ksub = (idx >> 2) & 1;
                int rg = idx & 3;
                const __bf16* A = mat ? hbf : aggb;
                src = A + (size_t)(nodeBlock + rg * 16 + r4) * DD + k0 + ksub * 32 + kb;
                dst = &sA[mat][ksub][rg * 16][0];
            } else {
                int j = idx - 16;          // 0..47
                int g6 = j >> 3;           // 0..5
                int ksub = (j >> 2) & 1;
                int rg = j & 3;
                const __bf16* B = (g6 < 3) ? bihw : whh;
                int brow = (g6 % 3) * 256 + colBlock + rg * 16 + r4;
                src = B + (size_t)brow * DD + k0 + ksub * 32 + kb;
                dst = &sB[g6][ksub][rg * 16][0];
            }
            gload_lds16(src, dst);
        }
        __syncthreads();

#pragma unroll
        for (int ksub = 0; ksub < 2; ksub++) {
            bf16x8 aA = *(const bf16x8*)&sA[0][ksub][nf * 16 + ln][quad * 8];
            bf16x8 aH = *(const bf16x8*)&sA[1][ksub][nf * 16 + ln][quad * 8];
#pragma unroll
            for (int g = 0; g < 3; g++) {
#pragma unroll
                for (int cc = 0; cc < 2; cc++) {
                    bf16x8 bI = *(const bf16x8*)&sB[g][ksub][ch + cc * 16 + ln][quad * 8];
                    bf16x8 bH = *(const bf16x8*)&sB[3 + g][ksub][ch + cc * 16 + ln][quad * 8];
                    acc[g][cc] = __builtin_amdgcn_mfma_f32_16x16x32_bf16(aA, bI, acc[g][cc], 0, 0, 0);
                    acc[3 + g][cc] = __builtin_amdgcn_mfma_f32_16x16x32_bf16(aH, bH, acc[3 + g][cc], 0, 0, 0);
                }
            }
        }
    }

    // epilogue: 16n x 32d per wave
#pragma unroll
    for (int r = 0; r < 4; r++) {
        int n = nodeBlock + nf * 16 + quad * 4 + r;
        if (n >= NN) continue;
#pragma unroll
        for (int cc = 0; cc < 2; cc++) {
            int d = colBlock + ch + cc * 16 + ln;
            float ir = acc[0][cc][r] + b_ih[d];
            float iz = acc[1][cc][r] + b_ih[d + 256];
            float in_ = acc[2][cc][r] + b_ih[d + 512];
            float hr = acc[3][cc][r] + b_hh[d];
            float hz = acc[4][cc][r] + b_hh[d + 256];
            float hn = acc[5][cc][r] + b_hh[d + 512];
            float rr = 1.f / (1.f + __expf(-(ir + hr)));
            float zz = 1.f / (1.f + __expf(-(iz + hz)));
            float ax = in_ + rr * hn;
            float e2 = __expf(-2.f * ax);
            float nnv = 2.f / (1.f + e2) - 1.f;
            float hp = hin[(size_t)n * DD + d];
            float o = (1.f - zz) * nnv + zz * hp;
            hout[(size_t)n * DD + d] = o;
            hbfout[(size_t)n * DD + d] = (__bf16)o;
        }
    }
}

// ---------------- launch ----------------

extern "C" void kernel_launch(void* const* d_in, const int* in_sizes, int n_in,
                              void* d_out, int out_size, void* d_ws, size_t ws_size,
                              hipStream_t stream) {
    const float* x = (const float*)d_in[0];
    const int* edge_index = (const int*)d_in[1];
    const float* edge_attr = (const float*)d_in[2];
    const float* weight = (const float*)d_in[3];
    const float* w_ih = (const float*)d_in[4];
    const float* w_hh = (const float*)d_in[5];
    const float* b_ih = (const float*)d_in[6];
    const float* b_hh = (const float*)d_in[7];

    size_t off = 0;
    char* base = (char*)d_ws;
    auto carve = [&](size_t bytes) -> void* {
        void* p = base + off;
        off += (bytes + 255) & ~(size_t)255;
        return p;
    };
    float* hb = (float*)carve((size_t)NPAD * DD * 4);
    __bf16* hbfA = (__bf16*)carve((size_t)NPAD * DD * 2);
    __bf16* hbfB = (__bf16*)carve((size_t)NPAD * DD * 2);
    __bf16* aggb = (__bf16*)carve((size_t)NPAD * DD * 2);
    __bf16* whhb = (__bf16*)carve((size_t)768 * DD * 2);
    __bf16* beff = (__bf16*)carve((size_t)LL * 768 * DD * 2);
    int* deg = (int*)carve((size_t)NN * 4);
    int* row_start = (int*)carve((size_t)(NN + 1) * 4);
    int* cursor = (int*)carve((size_t)NN * 4);
    int* ssrc = (int*)carve((size_t)EE * 4);
    float* sattr = (float*)carve((size_t)EE * 4);
    (void)ws_size;

    // setup (5 launches)
    prep_k<<<(NN * DD + 255) / 256, 256, 0, stream>>>(w_hh, x, whhb, hb, hbfA, hbfB,
                                                      aggb, deg);
    hist_k<<<(EE + 255) / 256, 256, 0, stream>>>(edge_index + EE, deg);
    scan_k<<<1, 1024, 0, stream>>>(deg, row_start, cursor);
    fill_k<<<(EE + 255) / 256, 256, 0, stream>>>(edge_index, edge_attr, cursor, ssrc, sattr);
    beff32_k<<<dim3(12, 4, LL), 256, 0, stream>>>(w_ih, weight, beff);

    float* hA = hb;
    float* hB = (float*)d_out;
    __bf16* hbfIn = hbfA;
    __bf16* hbfOut = hbfB;
    for (int l = 0; l < LL; l++) {
        aggregate_bf_k<<<2500, 256, 0, stream>>>(hbfIn, row_start, ssrc, sattr, aggb);
        gru_mfma_k<<<dim3(157, 4), 512, 0, stream>>>(aggb, hbfIn, hA,
                                                     beff + (size_t)l * 768 * DD, whhb,
                                                     b_ih, b_hh, hB, hbfOut);
        float* t = hA; hA = hB; hB = t;
        __bf16* tb = hbfIn; hbfIn = hbfOut; hbfOut = tb;
    }
    // 5 swaps: final h landed in d_out
}